// Round 4
// baseline (234.247 us; speedup 1.0000x reference)
//
#include <hip/hip_runtime.h>
#include <hip/hip_cooperative_groups.h>
#include <math.h>

namespace cg = cooperative_groups;

// x is [L][B] float32 row-major. out[b] = sum_i sigmoid(max_{j>=i} x[j][b]).
// sigmoid monotonic => scan raw x, apply sigmoid late.
constexpr int L = 8192;
constexpr int B = 4096;
constexpr int CH = 64;                 // rows per chunk
constexpr int NC = L / CH;             // 128 chunks
constexpr int TPB = 256;
constexpr int VEC = 4;                 // phase-1 float4
constexpr int COLS_PER_BLOCK = TPB * VEC;      // 1024
constexpr int COL_TILES = B / COLS_PER_BLOCK;  // 4
constexpr int NBLK = NC * COL_TILES;           // 512 blocks (2 per CU)
constexpr int STRIPS = B / TPB;                // 16 (phase-2 column strips)
constexpr int NSUB = NC * STRIPS;              // 2048 phase-2 subtasks

__device__ __forceinline__ float fast_sigmoid(float t) {
    return __builtin_amdgcn_rcpf(1.0f + __expf(-t));
}

__global__ __launch_bounds__(TPB, 2) void soft_len_fused(
        const float* __restrict__ x,
        float* __restrict__ cmax,      // [NC][B] per-chunk max (kept intact)
        float* __restrict__ carryBuf,  // [NC][B] exclusive suffix max
        float* __restrict__ partial,   // [NC][B] per-chunk sigmoid sums
        float* __restrict__ out)       // [B]
{
    cg::grid_group grid = cg::this_grid();
    const int bb = blockIdx.x;
    const int t  = threadIdx.x;

    // ---- Phase 1: per-chunk, per-column max. The mandatory 128 MiB HBM read.
    {
        const int chunk = bb / COL_TILES;
        const int tile  = bb % COL_TILES;
        const int col   = tile * COLS_PER_BLOCK + t * VEC;
        const float4* xin =
            reinterpret_cast<const float4*>(x + (size_t)chunk * CH * B + col);
        float4 m = make_float4(-INFINITY, -INFINITY, -INFINITY, -INFINITY);
        #pragma unroll 16
        for (int r = 0; r < CH; ++r) {
            float4 v = xin[(size_t)r * (B / VEC)];
            m.x = fmaxf(m.x, v.x);
            m.y = fmaxf(m.y, v.y);
            m.z = fmaxf(m.z, v.z);
            m.w = fmaxf(m.w, v.w);
        }
        *reinterpret_cast<float4*>(cmax + (size_t)chunk * B + col) = m;
    }
    grid.sync();

    // ---- Phase 1.5: exclusive suffix max over chunks (16 blocks, reg-array).
    if (bb < B / TPB) {
        const int col = bb * TPB + t;
        float run = -INFINITY;
        float v[NC / 2];
        // high half: chunks 127..64
        #pragma unroll
        for (int i = 0; i < NC / 2; ++i)
            v[i] = cmax[(size_t)(NC / 2 + i) * B + col];
        #pragma unroll
        for (int i = NC / 2 - 1; i >= 0; --i) {
            carryBuf[(size_t)(NC / 2 + i) * B + col] = run;
            run = fmaxf(run, v[i]);
        }
        // low half: chunks 63..0
        #pragma unroll
        for (int i = 0; i < NC / 2; ++i)
            v[i] = cmax[(size_t)i * B + col];
        #pragma unroll
        for (int i = NC / 2 - 1; i >= 0; --i) {
            carryBuf[(size_t)i * B + col] = run;
            run = fmaxf(run, v[i]);
        }
    }
    grid.sync();

    // ---- Phase 2: per-chunk contribution. KEY: if carry >= chunk max, the
    // tail max is constant over the chunk => contribution = CH*sigmoid(carry),
    // no x re-read. Only chunks holding a new running max (≈ln(NC)/col) rescan.
    #pragma unroll
    for (int q = 0; q < NSUB / NBLK; ++q) {         // 4 subtasks per block
        const int sub = bb + q * NBLK;
        const int c   = sub / STRIPS;
        const int s   = sub % STRIPS;
        const int col = s * TPB + t;
        const float a     = cmax[(size_t)c * B + col];
        const float carry = carryBuf[(size_t)c * B + col];
        float sum;
        if (carry >= a) {
            sum = (float)CH * fast_sigmoid(carry);
        } else {
            const float* xp = x + (size_t)c * CH * B + col;
            float tail = carry, sm = 0.f;
            #pragma unroll 16
            for (int r = CH - 1; r >= 0; --r) {
                tail = fmaxf(tail, xp[(size_t)r * B]);
                sm += fast_sigmoid(tail);
            }
            sum = sm;
        }
        partial[(size_t)c * B + col] = sum;
    }
    grid.sync();

    // ---- Phase 3: out[b] = sum over chunks of partial[c][b].
    {
        const int colo = t & 7;            // 8 cols per block
        const int k    = t >> 3;           // 32 chunk-slots
        const int col  = bb * 8 + colo;
        float s0 = 0.f;
        #pragma unroll
        for (int j = 0; j < 4; ++j)
            s0 += partial[(size_t)(k + 32 * j) * B + col];
        // reduce over k within each wave (k bits 3..5 of lane id)
        s0 += __shfl_xor(s0, 8);
        s0 += __shfl_xor(s0, 16);
        s0 += __shfl_xor(s0, 32);
        __shared__ float red[4][8];
        if ((t & 63) < 8) red[t >> 6][t & 7] = s0;
        __syncthreads();
        if (t < 8)
            out[bb * 8 + t] = red[0][t] + red[1][t] + red[2][t] + red[3][t];
    }
}

extern "C" void kernel_launch(void* const* d_in, const int* in_sizes, int n_in,
                              void* d_out, int out_size, void* d_ws, size_t ws_size,
                              hipStream_t stream) {
    const float* x = (const float*)d_in[0];
    float* out = (float*)d_out;

    // Workspace (6 MiB, all regions fully written before any read each call):
    float* cmax     = (float*)d_ws;                      // NC*B
    float* carryBuf = cmax + (size_t)NC * B;             // NC*B
    float* partial  = carryBuf + (size_t)NC * B;         // NC*B

    void* args[] = {(void*)&x, (void*)&cmax, (void*)&carryBuf,
                    (void*)&partial, (void*)&out};
    hipLaunchCooperativeKernel((const void*)soft_len_fused,
                               dim3(NBLK), dim3(TPB), args, 0, stream);
}

// Round 5
// 54.607 us; speedup vs baseline: 4.2897x; 4.2897x over previous
//
#include <hip/hip_runtime.h>
#include <math.h>

// x is [L][B] float32 row-major. out[b] = sum_i sigmoid(max_{j>=i} x[j][b]).
// sigmoid monotonic => scan raw x, apply sigmoid late.
// NO cross-block spinning/atomics anywhere: round-2 (decoupled lookback, 2 ms)
// and round-4 (grid.sync, 243 us) both showed cross-XCD polling is ~10-100x
// the cost of the actual work. Plain stream-ordered dispatches only.
constexpr int L = 8192;
constexpr int B = 4096;
constexpr int CH = 64;            // rows per chunk
constexpr int NC = L / CH;        // 128 chunks
constexpr int TPB = 256;
constexpr int VEC = 4;            // pass-1 float4
constexpr int COLS_PER_BLOCK = TPB * VEC;     // 1024
constexpr int COL_TILES = B / COLS_PER_BLOCK; // 4
constexpr int STRIPS = B / TPB;               // 16 column strips (pass 3)

__device__ __forceinline__ float fast_sigmoid(float t) {
    return __builtin_amdgcn_rcpf(1.0f + __expf(-t));
}

// Pass 1: cmax[c][b] = max over rows of chunk c. The mandatory HBM stream.
// Round-1-proven form (~20 us, ~6.7 TB/s).
__global__ __launch_bounds__(TPB) void soft_len_chunk_max(
        const float* __restrict__ x, float* __restrict__ cmax) {
    const int chunk = blockIdx.x;
    const int col = blockIdx.y * COLS_PER_BLOCK + threadIdx.x * VEC;
    const float4* xin =
        reinterpret_cast<const float4*>(x + (size_t)chunk * CH * B + col);
    float4 m = make_float4(-INFINITY, -INFINITY, -INFINITY, -INFINITY);
    #pragma unroll 8
    for (int r = 0; r < CH; ++r) {
        float4 v = xin[(size_t)r * (B / VEC)];
        m.x = fmaxf(m.x, v.x);
        m.y = fmaxf(m.y, v.y);
        m.z = fmaxf(m.z, v.z);
        m.w = fmaxf(m.w, v.w);
    }
    *reinterpret_cast<float4*>(cmax + (size_t)chunk * B + col) = m;
}

// Pass 2: exclusive suffix max across chunks per column, into carryBuf
// (cmax left intact for pass 3's skip test). Register-batched halves:
// 64 independent loads, scan in regs, 64 stores. 64 blocks x 64 threads.
__global__ __launch_bounds__(64) void soft_len_suffix_max(
        const float* __restrict__ cmax, float* __restrict__ carryBuf) {
    const int col = blockIdx.x * 64 + threadIdx.x;
    float run = -INFINITY;
    float v[NC / 2];
    #pragma unroll
    for (int h = 1; h >= 0; --h) {
        const int base = h * (NC / 2);
        #pragma unroll
        for (int i = 0; i < NC / 2; ++i)
            v[i] = cmax[(size_t)(base + i) * B + col];
        #pragma unroll
        for (int i = NC / 2 - 1; i >= 0; --i) {
            carryBuf[(size_t)(base + i) * B + col] = run;
            run = fmaxf(run, v[i]);
        }
    }
}

// Pass 3: per-chunk contribution with skip. If carry >= chunk max for ALL
// lanes of the wave (__any vote keeps the branch wave-uniform), the tail max
// is constant => CH*sigmoid(carry), no x re-read. Otherwise rescan the chunk
// (reads hit L3: x is 128 MiB < 256 MiB Infinity Cache).
__global__ __launch_bounds__(TPB) void soft_len_scan(
        const float* __restrict__ x, const float* __restrict__ cmax,
        const float* __restrict__ carryBuf, float* __restrict__ partial) {
    const int c   = blockIdx.x / STRIPS;
    const int s   = blockIdx.x % STRIPS;
    const int col = s * TPB + threadIdx.x;
    const float a     = cmax[(size_t)c * B + col];
    const float carry = carryBuf[(size_t)c * B + col];
    float sum;
    if (__any(carry < a)) {
        const float* xp = x + (size_t)c * CH * B + col;
        float tail = carry, sm = 0.f;
        #pragma unroll 8
        for (int r = CH - 1; r >= 0; --r) {
            tail = fmaxf(tail, xp[(size_t)r * B]);
            sm += fast_sigmoid(tail);
        }
        sum = sm;  // correct for every lane, incl. those with carry >= a
    } else {
        sum = (float)CH * fast_sigmoid(carry);
    }
    partial[(size_t)c * B + col] = sum;
}

// Pass 4: out[b] = sum over chunks of partial[c][b]. 64 blocks x 64 threads.
__global__ __launch_bounds__(64) void soft_len_reduce(
        const float* __restrict__ partial, float* __restrict__ out) {
    const int col = blockIdx.x * 64 + threadIdx.x;
    float s = 0.f;
    #pragma unroll 8
    for (int c = 0; c < NC; ++c) s += partial[(size_t)c * B + col];
    out[col] = s;
}

extern "C" void kernel_launch(void* const* d_in, const int* in_sizes, int n_in,
                              void* d_out, int out_size, void* d_ws, size_t ws_size,
                              hipStream_t stream) {
    const float* x = (const float*)d_in[0];
    float* out = (float*)d_out;

    // Workspace (6 MiB): every region fully written before any read each call.
    float* cmax     = (float*)d_ws;                  // [NC][B]
    float* carryBuf = cmax + (size_t)NC * B;         // [NC][B]
    float* partial  = carryBuf + (size_t)NC * B;     // [NC][B]

    soft_len_chunk_max<<<dim3(NC, COL_TILES), TPB, 0, stream>>>(x, cmax);
    soft_len_suffix_max<<<B / 64, 64, 0, stream>>>(cmax, carryBuf);
    soft_len_scan<<<NC * STRIPS, TPB, 0, stream>>>(x, cmax, carryBuf, partial);
    soft_len_reduce<<<B / 64, 64, 0, stream>>>(partial, out);
}